// Round 1
// baseline (702.001 us; speedup 1.0000x reference)
//
#include <hip/hip_runtime.h>

#define EPSI 1e-5f

__device__ __forceinline__ float lrelu(float x) { return x > 0.f ? x : 0.01f * x; }

// Block-wide sum of (a,b). blockDim.x == 256. Result broadcast to all threads.
__device__ __forceinline__ float2 block_reduce_sum2(float a, float b) {
    #pragma unroll
    for (int off = 1; off < 64; off <<= 1) {
        a += __shfl_xor(a, off, 64);
        b += __shfl_xor(b, off, 64);
    }
    __shared__ float lds[8];
    const int t = threadIdx.x;
    if ((t & 63) == 0) { lds[2 * (t >> 6)] = a; lds[2 * (t >> 6) + 1] = b; }
    __syncthreads();
    a = lds[0] + lds[2] + lds[4] + lds[6];
    b = lds[1] + lds[3] + lds[5] + lds[7];
    return make_float2(a, b);
}

// ---------------- K1: conv1(3->16, 2x2 s2) + InstanceNorm + lrelu ----------------
// grid: B*16 blocks, 256 threads. plane 64x64 = 4096, 16 outputs/thread.
__global__ __launch_bounds__(256) void k1_conv_in(const float* __restrict__ x,
                                                  const float* __restrict__ w1,
                                                  float* __restrict__ h1) {
    const int b = blockIdx.x;
    const int n = b >> 4, co = b & 15;
    const int t = threadIdx.x;
    float w[3][2][2];
    #pragma unroll
    for (int ic = 0; ic < 3; ++ic)
        #pragma unroll
        for (int kh = 0; kh < 2; ++kh)
            #pragma unroll
            for (int kw = 0; kw < 2; ++kw)
                w[ic][kh][kw] = w1[((co * 3 + ic) * 2 + kh) * 2 + kw];
    const float* xn = x + (size_t)n * 3 * 128 * 128;
    float r[16];
    float s1 = 0.f, s2 = 0.f;
    #pragma unroll
    for (int i = 0; i < 16; ++i) {
        const int idx = t + 256 * i;
        const int oy = idx >> 6, ox = idx & 63;
        float acc = 0.f;
        #pragma unroll
        for (int ic = 0; ic < 3; ++ic) {
            const float2* r0 = (const float2*)(xn + ic * 16384 + (2 * oy) * 128);
            const float2* r1 = (const float2*)(xn + ic * 16384 + (2 * oy + 1) * 128);
            const float2 v0 = r0[ox], v1 = r1[ox];
            acc += v0.x * w[ic][0][0] + v0.y * w[ic][0][1] + v1.x * w[ic][1][0] + v1.y * w[ic][1][1];
        }
        r[i] = acc;
        s1 += acc; s2 += acc * acc;
    }
    const float2 s = block_reduce_sum2(s1, s2);
    const float mean = s.x * (1.f / 4096.f);
    const float var = s.y * (1.f / 4096.f) - mean * mean;
    const float sc = rsqrtf(var + EPSI);
    float* o = h1 + ((size_t)n * 16 + co) * 4096;
    #pragma unroll
    for (int i = 0; i < 16; ++i)
        o[t + 256 * i] = lrelu((r[i] - mean) * sc);
}

// ---------------- K2: conv2(16->32) + IN + lrelu (labels cancel under IN) --------
// grid: B*32 blocks, 256 threads. plane 32x32 = 1024, 4 outputs/thread.
__global__ __launch_bounds__(256) void k2_conv_in(const float* __restrict__ h1,
                                                  const float* __restrict__ w2,
                                                  float* __restrict__ h2) {
    const int b = blockIdx.x;
    const int n = b >> 5, co = b & 31;
    const int t = threadIdx.x;
    const float* h1n = h1 + (size_t)n * 16 * 4096;
    const float* wc = w2 + (size_t)co * 36 * 4;  // [36][2][2]; only ic<16 used
    float acc[4] = {0.f, 0.f, 0.f, 0.f};
    #pragma unroll
    for (int ic = 0; ic < 16; ++ic) {
        const float w00 = wc[ic * 4 + 0], w01 = wc[ic * 4 + 1];
        const float w10 = wc[ic * 4 + 2], w11 = wc[ic * 4 + 3];
        const float* p = h1n + ic * 4096;
        #pragma unroll
        for (int j = 0; j < 4; ++j) {
            const int idx = t + 256 * j;
            const int oy = idx >> 5, ox = idx & 31;
            const float2 v0 = ((const float2*)(p + (2 * oy) * 64))[ox];
            const float2 v1 = ((const float2*)(p + (2 * oy + 1) * 64))[ox];
            acc[j] += v0.x * w00 + v0.y * w01 + v1.x * w10 + v1.y * w11;
        }
    }
    float s1 = 0.f, s2 = 0.f;
    #pragma unroll
    for (int j = 0; j < 4; ++j) { s1 += acc[j]; s2 += acc[j] * acc[j]; }
    const float2 s = block_reduce_sum2(s1, s2);
    const float mean = s.x * (1.f / 1024.f);
    const float var = s.y * (1.f / 1024.f) - mean * mean;
    const float sc = rsqrtf(var + EPSI);
    float* o = h2 + ((size_t)n * 32 + co) * 1024;
    #pragma unroll
    for (int j = 0; j < 4; ++j)
        o[t + 256 * j] = lrelu((acc[j] - mean) * sc);
}

// ---------------- K3: conv3(32->64) + IN + lrelu ---------------------------------
// grid: B*64 blocks, 256 threads. plane 16x16 = 256, 1 output/thread.
__global__ __launch_bounds__(256) void k3_conv_in(const float* __restrict__ h2,
                                                  const float* __restrict__ w3,
                                                  float* __restrict__ h3) {
    const int b = blockIdx.x;
    const int n = b >> 6, co = b & 63;
    const int t = threadIdx.x;
    const int oy = t >> 4, ox = t & 15;
    const float* h2n = h2 + (size_t)n * 32 * 1024;
    const float* wc = w3 + (size_t)co * 32 * 4;
    float acc = 0.f;
    #pragma unroll
    for (int ic = 0; ic < 32; ++ic) {
        const float w00 = wc[ic * 4 + 0], w01 = wc[ic * 4 + 1];
        const float w10 = wc[ic * 4 + 2], w11 = wc[ic * 4 + 3];
        const float* p = h2n + ic * 1024;
        const float2 v0 = ((const float2*)(p + (2 * oy) * 32))[ox];
        const float2 v1 = ((const float2*)(p + (2 * oy + 1) * 32))[ox];
        acc += v0.x * w00 + v0.y * w01 + v1.x * w10 + v1.y * w11;
    }
    const float2 s = block_reduce_sum2(acc, acc * acc);
    const float mean = s.x * (1.f / 256.f);
    const float var = s.y * (1.f / 256.f) - mean * mean;
    const float sc = rsqrtf(var + EPSI);
    h3[((size_t)n * 64 + co) * 256 + t] = lrelu((acc - mean) * sc);
}

// ---------------- K4: conv4(64->128) + IN + lrelu --------------------------------
// grid: B*128 blocks, 64 threads (1 wave). plane 8x8 = 64, 1 output/lane.
__global__ __launch_bounds__(64) void k4_conv_in(const float* __restrict__ h3,
                                                 const float* __restrict__ w4,
                                                 float* __restrict__ h4) {
    const int b = blockIdx.x;
    const int n = b >> 7, co = b & 127;
    const int l = threadIdx.x;
    const int oy = l >> 3, ox = l & 7;
    const float* h3n = h3 + (size_t)n * 64 * 256;
    const float* wc = w4 + (size_t)co * 64 * 4;
    float acc = 0.f;
    #pragma unroll 8
    for (int ic = 0; ic < 64; ++ic) {
        const float w00 = wc[ic * 4 + 0], w01 = wc[ic * 4 + 1];
        const float w10 = wc[ic * 4 + 2], w11 = wc[ic * 4 + 3];
        const float* p = h3n + ic * 256;
        const float2 v0 = ((const float2*)(p + (2 * oy) * 16))[ox];
        const float2 v1 = ((const float2*)(p + (2 * oy + 1) * 16))[ox];
        acc += v0.x * w00 + v0.y * w01 + v1.x * w10 + v1.y * w11;
    }
    float s1 = acc, s2 = acc * acc;
    #pragma unroll
    for (int off = 1; off < 64; off <<= 1) {
        s1 += __shfl_xor(s1, off, 64);
        s2 += __shfl_xor(s2, off, 64);
    }
    const float mean = s1 * (1.f / 64.f);
    const float var = s2 * (1.f / 64.f) - mean * mean;
    const float sc = rsqrtf(var + EPSI);
    h4[((size_t)n * 128 + co) * 64 + l] = lrelu((acc - mean) * sc);
}

// ---------------- K5: FC1 GEMM [256,8192]x[1024,8192]^T + bias + lrelu -----------
// BM=32 BN=64 BK=32; 256 threads; each thread 2x4 outputs. grid = 8*16 = 128.
__global__ __launch_bounds__(256) void k5_fc1(const float* __restrict__ A,
                                              const float* __restrict__ W,
                                              const float* __restrict__ bias,
                                              float* __restrict__ C) {
    __shared__ float As[32][32];  // [kk][m], m-pair XOR-swizzled
    __shared__ float Bs[32][64];  // [kk][n], n-quad XOR-swizzled
    const int t = threadIdx.x;
    const int mt = blockIdx.x >> 4;
    const int nt = blockIdx.x & 15;
    const int m0 = mt * 32, n0 = nt * 64;
    const int tx = t & 15;   // n-quad: cols 4tx..4tx+3
    const int ty = t >> 4;   // m-pair: rows 2ty, 2ty+1
    const int ar = t >> 3, ac4 = t & 7;   // A load: row, k-quad
    const int bn = t >> 2, bc4 = t & 3;   // B load: row(n), k-quad
    float acc[2][4] = {};
    for (int k0 = 0; k0 < 8192; k0 += 32) {
        const float4 av = *(const float4*)(A + (size_t)(m0 + ar) * 8192 + k0 + 4 * ac4);
        const float4 bv0 = *(const float4*)(W + (size_t)(n0 + bn) * 8192 + k0 + 4 * bc4);
        const float4 bv1 = *(const float4*)(W + (size_t)(n0 + bn) * 8192 + k0 + 16 + 4 * bc4);
        __syncthreads();
        {
            const float a[4] = {av.x, av.y, av.z, av.w};
            const float b0[4] = {bv0.x, bv0.y, bv0.z, bv0.w};
            const float b1[4] = {bv1.x, bv1.y, bv1.z, bv1.w};
            #pragma unroll
            for (int j = 0; j < 4; ++j) {
                const int kkA = 4 * ac4 + j;
                As[kkA][((((ar >> 1) ^ kkA) & 15) << 1) | (ar & 1)] = a[j];
                const int kk0 = 4 * bc4 + j;
                Bs[kk0][((((bn >> 2) ^ kk0) & 15) << 2) | (bn & 3)] = b0[j];
                const int kk1 = kk0 + 16;
                Bs[kk1][((((bn >> 2) ^ kk1) & 15) << 2) | (bn & 3)] = b1[j];
            }
        }
        __syncthreads();
        #pragma unroll
        for (int kk = 0; kk < 32; ++kk) {
            const float2 a2 = *(const float2*)&As[kk][((ty ^ kk) & 15) << 1];
            const float4 b4 = *(const float4*)&Bs[kk][((tx ^ kk) & 15) << 2];
            acc[0][0] += a2.x * b4.x; acc[0][1] += a2.x * b4.y;
            acc[0][2] += a2.x * b4.z; acc[0][3] += a2.x * b4.w;
            acc[1][0] += a2.y * b4.x; acc[1][1] += a2.y * b4.y;
            acc[1][2] += a2.y * b4.z; acc[1][3] += a2.y * b4.w;
        }
    }
    #pragma unroll
    for (int i = 0; i < 2; ++i) {
        const int m = m0 + 2 * ty + i;
        #pragma unroll
        for (int j = 0; j < 4; ++j) {
            const int nn = n0 + 4 * tx + j;
            C[(size_t)m * 1024 + nn] = lrelu(acc[i][j] + bias[nn]);
        }
    }
}

// ---------------- K6: FC2 [256,1024]x[1,1024]^T + bias ---------------------------
__global__ __launch_bounds__(256) void k6_fc2(const float* __restrict__ h5,
                                              const float* __restrict__ w,
                                              const float* __restrict__ b,
                                              float* __restrict__ out) {
    const int n = blockIdx.x, t = threadIdx.x;
    const float* r = h5 + (size_t)n * 1024;
    float s = 0.f;
    #pragma unroll
    for (int i = 0; i < 4; ++i) s += r[t + 256 * i] * w[t + 256 * i];
    const float2 red = block_reduce_sum2(s, 0.f);
    if (t == 0) out[n] = red.x + b[0];
}

extern "C" void kernel_launch(void* const* d_in, const int* in_sizes, int n_in,
                              void* d_out, int out_size, void* d_ws, size_t ws_size,
                              hipStream_t stream) {
    (void)in_sizes; (void)n_in; (void)out_size; (void)ws_size;
    const float* x    = (const float*)d_in[0];
    // d_in[1] labels: contribution is spatially constant -> cancelled exactly by InstanceNorm
    const float* w1   = (const float*)d_in[2];
    // d_in[3] b1, d_in[5] b2, d_in[7] b3, d_in[9] b4: cancelled exactly by InstanceNorm
    const float* w2   = (const float*)d_in[4];
    const float* w3   = (const float*)d_in[6];
    const float* w4   = (const float*)d_in[8];
    const float* fcw1 = (const float*)d_in[10];
    const float* fcb1 = (const float*)d_in[11];
    const float* fcw2 = (const float*)d_in[12];
    const float* fcb2 = (const float*)d_in[13];
    float* out = (float*)d_out;
    float* bufA = (float*)d_ws;          // 16,777,216 floats (67.1 MB)
    float* bufB = bufA + 16777216;       //  8,388,608 floats (33.5 MB)
    // h1=bufA, h2=bufB, h3=bufA, h4=bufB, h5=bufA (dead-buffer reuse)
    k1_conv_in<<<256 * 16, 256, 0, stream>>>(x, w1, bufA);
    k2_conv_in<<<256 * 32, 256, 0, stream>>>(bufA, w2, bufB);
    k3_conv_in<<<256 * 64, 256, 0, stream>>>(bufB, w3, bufA);
    k4_conv_in<<<256 * 128, 64, 0, stream>>>(bufA, w4, bufB);
    k5_fc1<<<128, 256, 0, stream>>>(bufB, fcw1, fcb1, bufA);
    k6_fc2<<<256, 256, 0, stream>>>(bufA, fcw2, fcb2, out);
}